// Round 15
// baseline (105.939 us; speedup 1.0000x reference)
//
#include <hip/hip_runtime.h>
#include <hip/hip_bf16.h>

typedef __attribute__((ext_vector_type(4))) float f32x4;
typedef __attribute__((ext_vector_type(8))) short bf16x8;
typedef unsigned short u16;
typedef unsigned int u32;

#define T_SEQ 2048
#define DMODEL 1024

__device__ __forceinline__ u16 f2bf(float f) {
    __hip_bfloat16 h = __float2bfloat16(f);
    return __builtin_bit_cast(unsigned short, h);
}
__device__ __forceinline__ u16 f2h(float f) {
    _Float16 h = (_Float16)f;
    return __builtin_bit_cast(unsigned short, h);
}
__device__ __forceinline__ float h2f(u16 b) {
    return (float)__builtin_bit_cast(_Float16, b);
}

typedef const void __attribute__((address_space(1))) gvoid_t;
typedef void __attribute__((address_space(3))) lvoid_t;
__device__ __forceinline__ void gload16(const void* g, void* l) {
    __builtin_amdgcn_global_load_lds((gvoid_t*)g, (lvoid_t*)l, 16, 0, 0);
}

// ---------------- fused prep: casts + rope tables + lambda ----------------
__device__ __forceinline__ void cast4(const float* __restrict__ s,
                                      u16* __restrict__ d, int u) {
    int i = u * 4;
    float4 v = *(const float4*)(s + i);
    ushort4 o;
    o.x = f2bf(v.x); o.y = f2bf(v.y); o.z = f2bf(v.z); o.w = f2bf(v.w);
    *(ushort4*)(d + i) = o;
}

__global__ __launch_bounds__(256) void prep(const float* __restrict__ x,
                                            const float* __restrict__ Wq,
                                            const float* __restrict__ Wk,
                                            const float* __restrict__ Wv,
                                            const float* __restrict__ Wp,
                                            u16* __restrict__ x_bf, u16* __restrict__ wq_bf,
                                            u16* __restrict__ wk_bf, u16* __restrict__ wv_bf,
                                            u16* __restrict__ wp_bf,
                                            float* __restrict__ cosT, float* __restrict__ sinT,
                                            const float* __restrict__ lq1, const float* __restrict__ lk1,
                                            const float* __restrict__ lq2, const float* __restrict__ lk2,
                                            float* __restrict__ lam) {
    int b = blockIdx.x;
    if (b < 6144) {
        int u = b * 256 + threadIdx.x;
        if (u < 524288)       cast4(x,  x_bf,  u);
        else if (u < 786432)  cast4(Wq, wq_bf, u - 524288);
        else if (u < 1048576) cast4(Wk, wk_bf, u - 786432);
        else if (u < 1310720) cast4(Wv, wv_bf, u - 1048576);
        else                  cast4(Wp, wp_bf, u - 1310720);
    } else if (b < 6400) {
        int i = (b - 6144) * 256 + threadIdx.x;   // < 2048*32
        int t = i >> 5, j = i & 31;
        float inv = powf(10000.0f, -(float)j * (1.0f / 32.0f));
        float fr = (float)t * inv;
        cosT[i] = cosf(fr);
        sinT[i] = sinf(fr);
    } else if (threadIdx.x == 0) {
        float s1 = 0.f, s2 = 0.f;
        for (int i = 0; i < 32; ++i) { s1 += lq1[i] * lk1[i]; s2 += lq2[i] * lk2[i]; }
        *lam = expf(s1) - expf(s2) + 0.35550906759096928f;
    }
}

// ---------------- GEMM main loop: acc = A[M,K] * B[N,K]^T (64x128 tile) -------
// BK=64, 16 K-steps, 2-buffer prefetch, counted vmcnt(6), XOR-swizzled LDS.
__device__ __forceinline__ void gemm_main64(const u16* __restrict__ A,
                                            const u16* __restrict__ B,
                                            int m0, int n0, int K,
                                            u16* lA, u16* lB, f32x4 acc[2][4]) {
    const int tid = threadIdx.x;
    const int lane = tid & 63;
    const int wid = tid >> 6;
    const int wr = (wid >> 1) * 32;
    const int wc = (wid & 1) * 64;
    const int fr = lane & 15;
    const int kc = lane >> 4;
    const char* Ab = (const char*)A;
    const char* Bb = (const char*)B;
    const int rowbytes = K * 2;
    const int S = K >> 6;   // 16 steps

    auto stage = [&](int s, int buf) {
        char* la = (char*)lA + buf * 8192;    // 64 x 128B
        char* lb = (char*)lB + buf * 16384;   // 128 x 128B
#pragma unroll
        for (int i = 0; i < 2; ++i) {
            int seg = i * 256 + tid;
            int row = seg >> 3, cb = (seg & 7) * 16;
            gload16(Ab + (size_t)(m0 + row) * rowbytes + s * 128 + (cb ^ ((row & 7) << 4)),
                    la + seg * 16);
        }
#pragma unroll
        for (int i = 0; i < 4; ++i) {
            int seg = i * 256 + tid;
            int row = seg >> 3, cb = (seg & 7) * 16;
            gload16(Bb + (size_t)(n0 + row) * rowbytes + s * 128 + (cb ^ ((row & 7) << 4)),
                    lb + seg * 16);
        }
    };

    stage(0, 0);
    for (int s = 0; s < S; ++s) {
        const int buf = s & 1;
        if (s + 1 < S) {
            stage(s + 1, buf ^ 1);
            asm volatile("s_waitcnt vmcnt(6)" ::: "memory");
        } else {
            asm volatile("s_waitcnt vmcnt(0)" ::: "memory");
        }
        __builtin_amdgcn_sched_barrier(0);
        __builtin_amdgcn_s_barrier();
        __builtin_amdgcn_sched_barrier(0);

        const char* la = (const char*)lA + buf * 8192;
        const char* lb = (const char*)lB + buf * 16384;
        bf16x8 a[2][2], b[4][2];
#pragma unroll
        for (int m = 0; m < 2; ++m)
#pragma unroll
            for (int kh = 0; kh < 2; ++kh) {
                int row = wr + m * 16 + fr;
                a[m][kh] = *(const bf16x8*)(la + row * 128 +
                                            ((kh * 64 + kc * 16) ^ ((row & 7) << 4)));
            }
#pragma unroll
        for (int n = 0; n < 4; ++n)
#pragma unroll
            for (int kh = 0; kh < 2; ++kh) {
                int row = wc + n * 16 + fr;
                b[n][kh] = *(const bf16x8*)(lb + row * 128 +
                                            ((kh * 64 + kc * 16) ^ ((row & 7) << 4)));
            }
#pragma unroll
        for (int m = 0; m < 2; ++m)
#pragma unroll
            for (int n = 0; n < 4; ++n)
#pragma unroll
                for (int kh = 0; kh < 2; ++kh)
                    acc[m][n] = __builtin_amdgcn_mfma_f32_16x16x32_bf16(a[m][kh], b[n][kh],
                                                                        acc[m][n], 0, 0, 0);
        __builtin_amdgcn_s_barrier();
    }
}

// fused QKV GEMM: grid (24, 32); x-tiles 0-7 -> Q, 8-15 -> K, 16-23 -> V.
__global__ __launch_bounds__(256) void gemm_qkv(const u16* __restrict__ A,
                                                const u16* __restrict__ wq,
                                                const u16* __restrict__ wk,
                                                const u16* __restrict__ wv,
                                                const float* __restrict__ cosT,
                                                const float* __restrict__ sinT,
                                                u16* __restrict__ q_bf,
                                                u16* __restrict__ k_bf,
                                                u16* __restrict__ vT) {
    __shared__ __align__(16) u16 lA[2 * 64 * 64];
    __shared__ __align__(16) u16 lB[2 * 128 * 64];
    const int nt = blockIdx.x;
    const int which = nt >> 3;
    const u16* B = (which == 0) ? wq : (which == 1) ? wk : wv;
    const int m0 = blockIdx.y * 64;
    const int n0 = (nt & 7) * 128;

    f32x4 acc[2][4] = {};
    gemm_main64(A, B, m0, n0, 1024, lA, lB, acc);

    const int lane = threadIdx.x & 63;
    const int wid = threadIdx.x >> 6;
    const int wr = (wid >> 1) * 32;
    const int wc = (wid & 1) * 64;
    const int fr = lane & 15;
    const int rr = (lane >> 4) * 4;

    if (which == 2) {
#pragma unroll
        for (int m = 0; m < 2; ++m) {
            int t0 = m0 + wr + m * 16 + rr;
#pragma unroll
            for (int n = 0; n < 4; ++n) {
                int cb = n0 + wc + n * 16 + fr;
                ushort4 w;
                w.x = f2bf(acc[m][n][0]);
                w.y = f2bf(acc[m][n][1]);
                w.z = f2bf(acc[m][n][2]);
                w.w = f2bf(acc[m][n][3]);
                *(ushort4*)(vT + (size_t)cb * T_SEQ + t0) = w;
            }
        }
        return;
    }

    const float oscale = (which == 0) ? 0.18033688011112042f : 1.0f;  // 0.125*log2(e)
    const int cb = n0 + wc;
    const int plane = ((cb >> 9) << 3) | ((cb >> 6) & 7);
    u16* dstp = ((which == 0) ? q_bf : k_bf) + (size_t)plane * T_SEQ * 64;
#pragma unroll
    for (int m = 0; m < 2; ++m)
#pragma unroll
        for (int r = 0; r < 4; ++r) {
            int t = m0 + wr + m * 16 + rr + r;
            float s2 = 0.f;
#pragma unroll
            for (int n = 0; n < 4; ++n) { float a = acc[m][n][r]; s2 += a * a; }
            s2 += __shfl_xor(s2, 1); s2 += __shfl_xor(s2, 2);
            s2 += __shfl_xor(s2, 4); s2 += __shfl_xor(s2, 8);
            float inv = rsqrtf(s2 * (1.0f / 64.0f) + 1.1920929e-7f);
#pragma unroll
            for (int n = 0; n < 4; ++n) {
                float a = acc[m][n][r] * inv;
                float p_ = acc[m][n ^ 2][r] * inv;
                int jj = ((n & 1) << 4) + fr;
                float c = cosT[t * 32 + jj], sn = sinT[t * 32 + jj];
                float ov = (n < 2) ? (a * c + p_ * sn) : (a * c - p_ * sn);
                dstp[(size_t)t * 64 + n * 16 + fr] = f2bf(ov * oscale);
            }
        }
}

// grid (8, 32): 64x128 tiles
__global__ __launch_bounds__(256) void gemm_proj(const u16* __restrict__ A,
                                                 const u16* __restrict__ B,
                                                 float* __restrict__ C) {
    __shared__ __align__(16) u16 lA[2 * 64 * 64];
    __shared__ __align__(16) u16 lB[2 * 128 * 64];
    const int m0 = blockIdx.y * 64;
    const int n0 = blockIdx.x * 128;
    f32x4 acc[2][4] = {};
    gemm_main64(A, B, m0, n0, 1024, lA, lB, acc);
    const int lane = threadIdx.x & 63;
    const int wid = threadIdx.x >> 6;
    const int wr = (wid >> 1) * 32;
    const int wc = (wid & 1) * 64;
    const int fr = lane & 15;
    const int rr = (lane >> 4) * 4;
#pragma unroll
    for (int m = 0; m < 2; ++m)
#pragma unroll
        for (int n = 0; n < 4; ++n)
#pragma unroll
            for (int r = 0; r < 4; ++r)
                C[(size_t)(m0 + wr + m * 16 + rr + r) * 1024 + (n0 + wc + n * 16 + fr)] =
                    acc[m][n][r];
}

// ---------------- flash attention: QBLK=128, KV tile 32, 4 waves x 32 rows ---
// 640 blocks x 256 threads. Each wave owns 2 MFMA column-groups (q=fr, q=16+fr)
// so K/V ds_reads + barriers + staging are amortized over 2x the q-rows.
// V paired-row layout; swapped QK^T + swapped PV; P in registers.
__global__ __launch_bounds__(256, 4) void attn_kernel(const u16* __restrict__ q_bf,
                                                      const u16* __restrict__ k_bf,
                                                      const u16* __restrict__ vT_bf,
                                                      u16* __restrict__ Oc,
                                                      float2* __restrict__ ml) {
    __shared__ __align__(16) u16 lK[2][32 * 64];   // 4KB each
    __shared__ __align__(16) u16 lV[2][64 * 64];   // 8KB each (paired-row V)

    const int tid = threadIdx.x, lane = tid & 63, wid = tid >> 6;
    const int bid = blockIdx.x;
    const int plane = bid & 15;
    const int u = bid >> 4;             // 0..39, ordered qt descending
    int qt, chunk;
    if (u < 16)      { qt = 15 - (u >> 2);              chunk = u & 3; }
    else if (u < 28) { int w = u - 16; qt = 11 - w / 3; chunk = w % 3; }
    else if (u < 36) { int w = u - 28; qt = 7 - (w >> 1); chunk = w & 1; }
    else             { qt = 3 - (u - 36);               chunk = 0; }
    const int ntot = 4 * qt + 4;        // KV half-tiles (32 each)
    const int tb = chunk * 16;
    const int te = min(tb + 16, ntot);
    const int q0 = qt * 128;
    const int h = plane & 7;

    const u16* qp = q_bf + (size_t)plane * T_SEQ * 64;
    const char* kp = (const char*)(k_bf + (size_t)plane * T_SEQ * 64);
    const char* vp = (const char*)(vT_bf + (size_t)h * 128 * T_SEQ);
    const int fr = lane & 15, kc = lane >> 4;
    const int qrow0 = q0 + wid * 32 + fr;       // group 0; group 1 = +16

    bf16x8 aq[2][2];
#pragma unroll
    for (int g = 0; g < 2; ++g)
#pragma unroll
        for (int kq = 0; kq < 2; ++kq)
            aq[g][kq] = *(const bf16x8*)(qp + (size_t)(qrow0 + g * 16) * 64 + kq * 32 + kc * 8);

    f32x4 o[2][8] = {};                 // o[g][n8][r] = O[q=qrow0+16g][d=n8*16+kc*4+r]
    float mi[2] = {-1e30f, -1e30f}, li[2] = {0.f, 0.f};
    const int srcA = fr + ((kc & 1) << 5);
    const int srcB = srcA + 16;
    const bool hi = kc >= 2;

    auto stage = [&](int b, int t) {
        int s0 = t << 5;   // KV tile = 32
        {
            int row = tid >> 3, cp = (tid & 7) * 16;
            gload16(kp + (size_t)(s0 + row) * 128 + (cp ^ ((row & 7) << 4)),
                    (char*)lK[b] + tid * 16);
        }
#pragma unroll
        for (int i = 0; i < 2; ++i) {
            int c = i * 256 + tid;
            int row = c >> 3, cb = (c & 7) * 16;
            int cbs = cb ^ ((row & 7) << 4);
            int d = row * 2 + (cbs >> 6);
            int kk = (cbs & 63) >> 1;
            gload16(vp + (size_t)d * (T_SEQ * 2) + (size_t)(s0 + kk) * 2,
                    (char*)lV[b] + c * 16);
        }
    };

    auto compute = [&](const char* lKb, const char* lVb, int s0, bool diag) {
        // K fragments read once, used by both groups
        bf16x8 bk[2][2];
#pragma unroll
        for (int kq = 0; kq < 2; ++kq)
#pragma unroll
            for (int n = 0; n < 2; ++n) {
                int row = n * 16 + fr;
                bk[kq][n] = *(const bf16x8*)(lKb + row * 128 +
                                             ((kq * 64 + kc * 16) ^ ((row & 7) << 4)));
            }
        f32x4 sacc[2][2] = {};
        __builtin_amdgcn_s_setprio(1);
#pragma unroll
        for (int g = 0; g < 2; ++g)
#pragma unroll
            for (int kq = 0; kq < 2; ++kq)
#pragma unroll
                for (int n = 0; n < 2; ++n)
                    sacc[g][n] = __builtin_amdgcn_mfma_f32_16x16x32_bf16(bk[kq][n], aq[g][kq],
                                                                         sacc[g][n], 0, 0, 0);
        __builtin_amdgcn_s_setprio(0);

        u32 w32[2][2][2];
#pragma unroll
        for (int g = 0; g < 2; ++g) {
            const int qrow = qrow0 + g * 16;
            if (diag) {
#pragma unroll
                for (int n = 0; n < 2; ++n)
#pragma unroll
                    for (int r = 0; r < 4; ++r)
                        if (s0 + n * 16 + kc * 4 + r > qrow) sacc[g][n][r] = -1e30f;
            }
            float rmax = -1e30f;
#pragma unroll
            for (int n = 0; n < 2; ++n)
#pragma unroll
                for (int r = 0; r < 4; ++r)
                    rmax = fmaxf(rmax, sacc[g][n][r]);
            rmax = fmaxf(rmax, __shfl_xor(rmax, 16));
            rmax = fmaxf(rmax, __shfl_xor(rmax, 32));

            bool raise = rmax > mi[g] + 8.0f;   // T13 defer-max
            float f = raise ? __builtin_exp2f(mi[g] - rmax) : 1.0f;
            if (raise) mi[g] = rmax;

            float rs = 0.f;
#pragma unroll
            for (int n = 0; n < 2; ++n)
#pragma unroll
                for (int r = 0; r < 4; ++r) {
                    float p = __builtin_exp2f(sacc[g][n][r] - mi[g]);
                    sacc[g][n][r] = p;
                    rs += p;
                }
            rs += __shfl_xor(rs, 16);
            rs += __shfl_xor(rs, 32);
            li[g] = li[g] * f + rs;

            if (__any(raise)) {
#pragma unroll
                for (int n8 = 0; n8 < 8; ++n8)
#pragma unroll
                    for (int r = 0; r < 4; ++r) o[g][n8][r] *= f;
            }
#pragma unroll
            for (int n = 0; n < 2; ++n)
#pragma unroll
                for (int w = 0; w < 2; ++w) {
                    u32 rpk;
                    asm("v_cvt_pk_bf16_f32 %0, %1, %2"
                        : "=v"(rpk) : "v"(sacc[g][n][2 * w]), "v"(sacc[g][n][2 * w + 1]));
                    w32[g][n][w] = rpk;
                }
        }

        // redistribute per group: ap_g = P_g[k=kc*8+j][q=fr]
        union { u32 u4[4]; bf16x8 v; } ap[2];
#pragma unroll
        for (int g = 0; g < 2; ++g) {
            u32 a0 = (u32)__shfl((int)w32[g][0][0], srcA);
            u32 a1 = (u32)__shfl((int)w32[g][0][1], srcA);
            u32 a2 = (u32)__shfl((int)w32[g][0][0], srcB);
            u32 a3 = (u32)__shfl((int)w32[g][0][1], srcB);
            u32 b0 = (u32)__shfl((int)w32[g][1][0], srcA);
            u32 b1 = (u32)__shfl((int)w32[g][1][1], srcA);
            u32 b2 = (u32)__shfl((int)w32[g][1][0], srcB);
            u32 b3 = (u32)__shfl((int)w32[g][1][1], srcB);
            ap[g].u4[0] = hi ? b0 : a0;
            ap[g].u4[1] = hi ? b1 : a1;
            ap[g].u4[2] = hi ? b2 : a2;
            ap[g].u4[3] = hi ? b3 : a3;
        }

        // PV: V fragments read once, 2 mfma each (one per group)
        __builtin_amdgcn_s_setprio(1);
#pragma unroll
        for (int n8 = 0; n8 < 8; ++n8) {
            int d = n8 * 16 + fr;
            int row = d >> 1;
            int colb = (d & 1) * 64 + kc * 16;
            bf16x8 bv = *(const bf16x8*)(lVb + row * 128 + (colb ^ ((row & 7) << 4)));
            o[0][n8] = __builtin_amdgcn_mfma_f32_16x16x32_bf16(bv, ap[0].v, o[0][n8], 0, 0, 0);
            o[1][n8] = __builtin_amdgcn_mfma_f32_16x16x32_bf16(bv, ap[1].v, o[1][n8], 0, 0, 0);
        }
        __builtin_amdgcn_s_setprio(0);
    };

    stage(0, tb);
    for (int t = tb; t < te; ++t) {
        int ib = (t - tb) & 1;
        if (t + 1 < te) {
            stage(ib ^ 1, t + 1);
            asm volatile("s_waitcnt vmcnt(3)" ::: "memory");
        } else {
            asm volatile("s_waitcnt vmcnt(0)" ::: "memory");
        }
        __builtin_amdgcn_sched_barrier(0);
        __builtin_amdgcn_s_barrier();
        __builtin_amdgcn_sched_barrier(0);
        compute((const char*)lK[ib], (const char*)lV[ib], t << 5, t >= ntot - 4);
        __builtin_amdgcn_s_barrier();
    }

    // epilogue: normalized O (fp16) + (m,l) per group
#pragma unroll
    for (int g = 0; g < 2; ++g) {
        const float inv_l = 1.0f / li[g];
        u16* Ob = Oc + ((size_t)(plane * 4 + chunk) * T_SEQ + qrow0 + g * 16) * 128;
#pragma unroll
        for (int n8 = 0; n8 < 8; ++n8) {
            ushort4 w;
            w.x = f2h(o[g][n8][0] * inv_l);
            w.y = f2h(o[g][n8][1] * inv_l);
            w.z = f2h(o[g][n8][2] * inv_l);
            w.w = f2h(o[g][n8][3] * inv_l);
            *(ushort4*)(Ob + n8 * 16 + kc * 4) = w;
        }
        if (kc == 0)
            ml[(size_t)(plane * 4 + chunk) * T_SEQ + qrow0 + g * 16] = make_float2(mi[g], li[g]);
    }
}

// ---------------- merge chunks + diff (y1 - lambda*y2) -> bf16 ----------------
__global__ __launch_bounds__(256) void merge_kernel(const u16* __restrict__ Oc,
                                                    const float2* __restrict__ ml,
                                                    const float* __restrict__ lamp,
                                                    u16* __restrict__ yc) {
    int uu = blockIdx.x * 256 + threadIdx.x;   // < 524288
    int t = uu >> 8, rem = uu & 255, h = rem >> 5, d4 = (rem & 31) * 4;
    int qt = t >> 7;                           // QBLK = 128
    int nc = (4 * qt + 19) >> 4;               // ceil((4qt+4)/16)
    float lamv = *lamp;
    float yv[2][4];
#pragma unroll
    for (int v = 0; v < 2; ++v) {
        int plane = v * 8 + h;
        float2 m_l[4];
        float M = -1e30f;
#pragma unroll
        for (int c = 0; c < 4; ++c)
            if (c < nc) {
                m_l[c] = ml[(size_t)(plane * 4 + c) * T_SEQ + t];
                M = fmaxf(M, m_l[c].x);
            }
        float den = 0.f, a0 = 0.f, a1 = 0.f, a2 = 0.f, a3 = 0.f;
#pragma unroll
        for (int c = 0; c < 4; ++c)
            if (c < nc) {
                float w = __builtin_exp2f(m_l[c].x - M) * m_l[c].y;
                den += w;
                ushort4 ov = *(const ushort4*)(Oc +
                    ((size_t)(plane * 4 + c) * T_SEQ + t) * 128 + d4);
                a0 += w * h2f(ov.x);
                a1 += w * h2f(ov.y);
                a2 += w * h2f(ov.z);
                a3 += w * h2f(ov.w);
            }
        float inv = 1.0f / den;
        yv[v][0] = a0 * inv; yv[v][1] = a1 * inv;
        yv[v][2] = a2 * inv; yv[v][3] = a3 * inv;
    }
    ushort4 o;
    o.x = f2bf(yv[0][0] - lamv * yv[1][0]);
    o.y = f2bf(yv[0][1] - lamv * yv[1][1]);
    o.z = f2bf(yv[0][2] - lamv * yv[1][2]);
    o.w = f2bf(yv[0][3] - lamv * yv[1][3]);
    *(ushort4*)(yc + (size_t)t * 1024 + h * 128 + d4) = o;
}

extern "C" void kernel_launch(void* const* d_in, const int* in_sizes, int n_in,
                              void* d_out, int out_size, void* d_ws, size_t ws_size,
                              hipStream_t stream) {
    const float* x   = (const float*)d_in[0];
    const float* Wq  = (const float*)d_in[1];
    const float* Wk  = (const float*)d_in[2];
    const float* Wv  = (const float*)d_in[3];
    const float* Wp  = (const float*)d_in[4];
    const float* lq1 = (const float*)d_in[5];
    const float* lk1 = (const float*)d_in[6];
    const float* lq2 = (const float*)d_in[7];
    const float* lk2 = (const float*)d_in[8];
    float* out = (float*)d_out;

    char* ws = (char*)d_ws;
    u16*    x_bf  = (u16*)(ws);                        //  4 MB
    u16*    wq_bf = (u16*)(ws + (4ull << 20));
    u16*    wk_bf = (u16*)(ws + (6ull << 20));
    u16*    wv_bf = (u16*)(ws + (8ull << 20));
    u16*    wp_bf = (u16*)(ws + (10ull << 20));
    u16*    vT_bf = (u16*)(ws + (12ull << 20));        //  4 MB
    u16*    q_bf  = (u16*)(ws + (16ull << 20));        //  4 MB
    u16*    k_bf  = (u16*)(ws + (20ull << 20));        //  4 MB
    u16*    Oc    = (u16*)(ws + (24ull << 20));        // 32 MB (fp16)
    float2* ml    = (float2*)(ws + (56ull << 20));     //  1 MB
    u16*    yc_bf = (u16*)(ws + (57ull << 20));        //  4 MB
    float*  cosT  = (float*)(ws + (61ull << 20));
    float*  sinT  = (float*)(ws + (61ull << 20) + (256ull << 10));
    float*  lam   = (float*)(ws + (61ull << 20) + (512ull << 10));

    prep<<<6401, 256, 0, stream>>>(x, Wq, Wk, Wv, Wp,
                                   x_bf, wq_bf, wk_bf, wv_bf, wp_bf,
                                   cosT, sinT, lq1, lk1, lq2, lk2, lam);

    gemm_qkv<<<dim3(24, 32), 256, 0, stream>>>(x_bf, wq_bf, wk_bf, wv_bf,
                                               cosT, sinT, q_bf, k_bf, vT_bf);

    attn_kernel<<<640, 256, 0, stream>>>(q_bf, k_bf, vT_bf, Oc, ml);

    merge_kernel<<<2048, 256, 0, stream>>>(Oc, ml, lam, yc_bf);

    gemm_proj<<<dim3(8, 32), 256, 0, stream>>>(yc_bf, wp_bf, out);
}

// Round 16
// 90.677 us; speedup vs baseline: 1.1683x; 1.1683x over previous
//
#include <hip/hip_runtime.h>
#include <hip/hip_bf16.h>

typedef __attribute__((ext_vector_type(4))) float f32x4;
typedef __attribute__((ext_vector_type(8))) short bf16x8;
typedef unsigned short u16;
typedef unsigned int u32;

#define T_SEQ 2048
#define DMODEL 1024

__device__ __forceinline__ u16 f2bf(float f) {
    __hip_bfloat16 h = __float2bfloat16(f);
    return __builtin_bit_cast(unsigned short, h);
}
__device__ __forceinline__ u16 f2h(float f) {
    _Float16 h = (_Float16)f;
    return __builtin_bit_cast(unsigned short, h);
}
__device__ __forceinline__ float h2f(u16 b) {
    return (float)__builtin_bit_cast(_Float16, b);
}

typedef const void __attribute__((address_space(1))) gvoid_t;
typedef void __attribute__((address_space(3))) lvoid_t;
__device__ __forceinline__ void gload16(const void* g, void* l) {
    __builtin_amdgcn_global_load_lds((gvoid_t*)g, (lvoid_t*)l, 16, 0, 0);
}

// ---------------- fused prep: casts + rope tables + lambda ----------------
__device__ __forceinline__ void cast4(const float* __restrict__ s,
                                      u16* __restrict__ d, int u) {
    int i = u * 4;
    float4 v = *(const float4*)(s + i);
    ushort4 o;
    o.x = f2bf(v.x); o.y = f2bf(v.y); o.z = f2bf(v.z); o.w = f2bf(v.w);
    *(ushort4*)(d + i) = o;
}

__global__ __launch_bounds__(256) void prep(const float* __restrict__ x,
                                            const float* __restrict__ Wq,
                                            const float* __restrict__ Wk,
                                            const float* __restrict__ Wv,
                                            const float* __restrict__ Wp,
                                            u16* __restrict__ x_bf, u16* __restrict__ wq_bf,
                                            u16* __restrict__ wk_bf, u16* __restrict__ wv_bf,
                                            u16* __restrict__ wp_bf,
                                            float* __restrict__ cosT, float* __restrict__ sinT,
                                            const float* __restrict__ lq1, const float* __restrict__ lk1,
                                            const float* __restrict__ lq2, const float* __restrict__ lk2,
                                            float* __restrict__ lam) {
    int b = blockIdx.x;
    if (b < 6144) {
        int u = b * 256 + threadIdx.x;
        if (u < 524288)       cast4(x,  x_bf,  u);
        else if (u < 786432)  cast4(Wq, wq_bf, u - 524288);
        else if (u < 1048576) cast4(Wk, wk_bf, u - 786432);
        else if (u < 1310720) cast4(Wv, wv_bf, u - 1048576);
        else                  cast4(Wp, wp_bf, u - 1310720);
    } else if (b < 6400) {
        int i = (b - 6144) * 256 + threadIdx.x;   // < 2048*32
        int t = i >> 5, j = i & 31;
        float inv = powf(10000.0f, -(float)j * (1.0f / 32.0f));
        float fr = (float)t * inv;
        cosT[i] = cosf(fr);
        sinT[i] = sinf(fr);
    } else if (threadIdx.x == 0) {
        float s1 = 0.f, s2 = 0.f;
        for (int i = 0; i < 32; ++i) { s1 += lq1[i] * lk1[i]; s2 += lq2[i] * lk2[i]; }
        *lam = expf(s1) - expf(s2) + 0.35550906759096928f;
    }
}

// ---------------- GEMM main loop: acc = A[M,K] * B[N,K]^T (64x128 tile) -------
// BK=64, 16 K-steps. 2-buffer prefetch: [stage(next) -> wait own vmcnt(6) ->
// barrier -> compute -> barrier]. 128B LDS rows, both-sides XOR swizzle.
__device__ __forceinline__ void gemm_main64(const u16* __restrict__ A,
                                            const u16* __restrict__ B,
                                            int m0, int n0, int K,
                                            u16* lA, u16* lB, f32x4 acc[2][4]) {
    const int tid = threadIdx.x;
    const int lane = tid & 63;
    const int wid = tid >> 6;
    const int wr = (wid >> 1) * 32;
    const int wc = (wid & 1) * 64;
    const int fr = lane & 15;
    const int kc = lane >> 4;
    const char* Ab = (const char*)A;
    const char* Bb = (const char*)B;
    const int rowbytes = K * 2;
    const int S = K >> 6;   // 16 steps

    auto stage = [&](int s, int buf) {
        char* la = (char*)lA + buf * 8192;    // 64 x 128B
        char* lb = (char*)lB + buf * 16384;   // 128 x 128B
#pragma unroll
        for (int i = 0; i < 2; ++i) {         // lA: 512 segs
            int seg = i * 256 + tid;
            int row = seg >> 3, cb = (seg & 7) * 16;
            gload16(Ab + (size_t)(m0 + row) * rowbytes + s * 128 + (cb ^ ((row & 7) << 4)),
                    la + seg * 16);
        }
#pragma unroll
        for (int i = 0; i < 4; ++i) {         // lB: 1024 segs
            int seg = i * 256 + tid;
            int row = seg >> 3, cb = (seg & 7) * 16;
            gload16(Bb + (size_t)(n0 + row) * rowbytes + s * 128 + (cb ^ ((row & 7) << 4)),
                    lb + seg * 16);
        }
    };

    stage(0, 0);
    for (int s = 0; s < S; ++s) {
        const int buf = s & 1;
        if (s + 1 < S) {
            stage(s + 1, buf ^ 1);
            asm volatile("s_waitcnt vmcnt(6)" ::: "memory");   // own stage(s) done
        } else {
            asm volatile("s_waitcnt vmcnt(0)" ::: "memory");
        }
        __builtin_amdgcn_sched_barrier(0);
        __builtin_amdgcn_s_barrier();          // all waves: stage(s) complete
        __builtin_amdgcn_sched_barrier(0);

        const char* la = (const char*)lA + buf * 8192;
        const char* lb = (const char*)lB + buf * 16384;
        bf16x8 a[2][2], b[4][2];
#pragma unroll
        for (int m = 0; m < 2; ++m)
#pragma unroll
            for (int kh = 0; kh < 2; ++kh) {
                int row = wr + m * 16 + fr;
                a[m][kh] = *(const bf16x8*)(la + row * 128 +
                                            ((kh * 64 + kc * 16) ^ ((row & 7) << 4)));
            }
#pragma unroll
        for (int n = 0; n < 4; ++n)
#pragma unroll
            for (int kh = 0; kh < 2; ++kh) {
                int row = wc + n * 16 + fr;
                b[n][kh] = *(const bf16x8*)(lb + row * 128 +
                                            ((kh * 64 + kc * 16) ^ ((row & 7) << 4)));
            }
#pragma unroll
        for (int m = 0; m < 2; ++m)
#pragma unroll
            for (int n = 0; n < 4; ++n)
#pragma unroll
                for (int kh = 0; kh < 2; ++kh)
                    acc[m][n] = __builtin_amdgcn_mfma_f32_16x16x32_bf16(a[m][kh], b[n][kh],
                                                                        acc[m][n], 0, 0, 0);
        __builtin_amdgcn_s_barrier();          // compute(s) reads done before overwrite
    }
}

// fused QKV GEMM: grid (24, 32); x-tiles 0-7 -> Q, 8-15 -> K, 16-23 -> V.
// Q epilogue folds in attn scale*log2(e). V epilogue writes vT[d][t] directly.
__global__ __launch_bounds__(256) void gemm_qkv(const u16* __restrict__ A,
                                                const u16* __restrict__ wq,
                                                const u16* __restrict__ wk,
                                                const u16* __restrict__ wv,
                                                const float* __restrict__ cosT,
                                                const float* __restrict__ sinT,
                                                u16* __restrict__ q_bf,
                                                u16* __restrict__ k_bf,
                                                u16* __restrict__ vT) {
    __shared__ __align__(16) u16 lA[2 * 64 * 64];
    __shared__ __align__(16) u16 lB[2 * 128 * 64];
    const int nt = blockIdx.x;
    const int which = nt >> 3;
    const u16* B = (which == 0) ? wq : (which == 1) ? wk : wv;
    const int m0 = blockIdx.y * 64;
    const int n0 = (nt & 7) * 128;

    f32x4 acc[2][4] = {};
    gemm_main64(A, B, m0, n0, 1024, lA, lB, acc);

    const int lane = threadIdx.x & 63;
    const int wid = threadIdx.x >> 6;
    const int wr = (wid >> 1) * 32;
    const int wc = (wid & 1) * 64;
    const int fr = lane & 15;
    const int rr = (lane >> 4) * 4;

    if (which == 2) {
        // transposed V write: vT[cb][t0..t0+3], cb = global col = h*128+d
#pragma unroll
        for (int m = 0; m < 2; ++m) {
            int t0 = m0 + wr + m * 16 + rr;
#pragma unroll
            for (int n = 0; n < 4; ++n) {
                int cb = n0 + wc + n * 16 + fr;
                ushort4 w;
                w.x = f2bf(acc[m][n][0]);
                w.y = f2bf(acc[m][n][1]);
                w.z = f2bf(acc[m][n][2]);
                w.w = f2bf(acc[m][n][3]);
                *(ushort4*)(vT + (size_t)cb * T_SEQ + t0) = w;
            }
        }
        return;
    }

    const float oscale = (which == 0) ? 0.18033688011112042f : 1.0f;  // 0.125*log2(e)
    const int cb = n0 + wc;
    const int plane = ((cb >> 9) << 3) | ((cb >> 6) & 7);
    u16* dstp = ((which == 0) ? q_bf : k_bf) + (size_t)plane * T_SEQ * 64;
#pragma unroll
    for (int m = 0; m < 2; ++m)
#pragma unroll
        for (int r = 0; r < 4; ++r) {
            int t = m0 + wr + m * 16 + rr + r;
            float s2 = 0.f;
#pragma unroll
            for (int n = 0; n < 4; ++n) { float a = acc[m][n][r]; s2 += a * a; }
            s2 += __shfl_xor(s2, 1); s2 += __shfl_xor(s2, 2);
            s2 += __shfl_xor(s2, 4); s2 += __shfl_xor(s2, 8);
            float inv = rsqrtf(s2 * (1.0f / 64.0f) + 1.1920929e-7f);
#pragma unroll
            for (int n = 0; n < 4; ++n) {
                float a = acc[m][n][r] * inv;
                float p_ = acc[m][n ^ 2][r] * inv;
                int jj = ((n & 1) << 4) + fr;
                float c = cosT[t * 32 + jj], sn = sinT[t * 32 + jj];
                float ov = (n < 2) ? (a * c + p_ * sn) : (a * c - p_ * sn);
                dstp[(size_t)t * 64 + n * 16 + fr] = f2bf(ov * oscale);
            }
        }
}

// grid (8, 32): 64x128 tiles
__global__ __launch_bounds__(256) void gemm_proj(const u16* __restrict__ A,
                                                 const u16* __restrict__ B,
                                                 float* __restrict__ C) {
    __shared__ __align__(16) u16 lA[2 * 64 * 64];
    __shared__ __align__(16) u16 lB[2 * 128 * 64];
    const int m0 = blockIdx.y * 64;
    const int n0 = blockIdx.x * 128;
    f32x4 acc[2][4] = {};
    gemm_main64(A, B, m0, n0, 1024, lA, lB, acc);
    const int lane = threadIdx.x & 63;
    const int wid = threadIdx.x >> 6;
    const int wr = (wid >> 1) * 32;
    const int wc = (wid & 1) * 64;
    const int fr = lane & 15;
    const int rr = (lane >> 4) * 4;
#pragma unroll
    for (int m = 0; m < 2; ++m)
#pragma unroll
        for (int n = 0; n < 4; ++n)
#pragma unroll
            for (int r = 0; r < 4; ++r)
                C[(size_t)(m0 + wr + m * 16 + rr + r) * 1024 + (n0 + wc + n * 16 + fr)] =
                    acc[m][n][r];
}

// ---------------- flash attention: QBLK=64, KV tile 32, 4-wave blocks --------
// 1280 blocks x 256 threads, 24KB LDS -> 6 blocks/CU. Chunks <= 16 half-tiles.
// V staged in paired-row layout [d>>1][(d&1)*32+k] (128B rows, XOR swizzle).
// Swapped QK^T + swapped PV; P in registers (cvt_pk + 8 bpermute + 4 select).
__global__ __launch_bounds__(256, 6) void attn_kernel(const u16* __restrict__ q_bf,
                                                      const u16* __restrict__ k_bf,
                                                      const u16* __restrict__ vT_bf,
                                                      u16* __restrict__ Oc,
                                                      float2* __restrict__ ml) {
    __shared__ __align__(16) u16 lK[2][32 * 64];   // 4KB each
    __shared__ __align__(16) u16 lV[2][64 * 64];   // 8KB each (paired-row V)

    const int tid = threadIdx.x, lane = tid & 63, wid = tid >> 6;
    const int bid = blockIdx.x;
    const int plane = bid & 15;
    const int u = bid >> 4;             // 0..79, ordered qt descending
    int qt, chunk;
    if (u < 32)      { qt = 31 - (u >> 2);              chunk = u & 3; }
    else if (u < 56) { int w = u - 32; qt = 23 - w / 3; chunk = w % 3; }
    else if (u < 72) { int w = u - 56; qt = 15 - (w >> 1); chunk = w & 1; }
    else             { qt = 7 - (u - 72);               chunk = 0; }
    const int ntot = 2 * qt + 2;        // KV half-tiles (32 each)
    const int tb = chunk * 16;
    const int te = min(tb + 16, ntot);
    const int q0 = qt * 64;
    const int h = plane & 7;

    const u16* qp = q_bf + (size_t)plane * T_SEQ * 64;
    const char* kp = (const char*)(k_bf + (size_t)plane * T_SEQ * 64);
    const char* vp = (const char*)(vT_bf + (size_t)h * 128 * T_SEQ);
    const int fr = lane & 15, kc = lane >> 4;
    const int qrow = q0 + wid * 16 + fr;

    bf16x8 aq[2];
#pragma unroll
    for (int kq = 0; kq < 2; ++kq)
        aq[kq] = *(const bf16x8*)(qp + (size_t)qrow * 64 + kq * 32 + kc * 8);

    f32x4 o[8] = {};                    // O^T: o[n8][r] = O[q=fr][d=n8*16+kc*4+r]
    float mi_l = -1e30f, li_l = 0.f;
    const int srcA = fr + ((kc & 1) << 5);
    const int srcB = srcA + 16;
    const bool hi = kc >= 2;            // n-select = kc>>1

    auto stage = [&](int b, int t) {
        int s0 = t << 5;   // KV tile = 32
        {   // K: 32 rows x 64d = 4KB, 128B rows, standard swizzle
            int row = tid >> 3, cp = (tid & 7) * 16;
            gload16(kp + (size_t)(s0 + row) * 128 + (cp ^ ((row & 7) << 4)),
                    (char*)lK[b] + tid * 16);
        }
#pragma unroll
        for (int i = 0; i < 2; ++i) {   // V paired-row: cell(row,cb) <- logical(row, cb^swz)
            int c = i * 256 + tid;
            int row = c >> 3, cb = (c & 7) * 16;
            int cbs = cb ^ ((row & 7) << 4);
            int d = row * 2 + (cbs >> 6);
            int kk = (cbs & 63) >> 1;
            gload16(vp + (size_t)d * (T_SEQ * 2) + (size_t)(s0 + kk) * 2,
                    (char*)lV[b] + c * 16);
        }
    };

    auto compute = [&](const char* lKb, const char* lVb, int s0, bool diag) {
        // S^T (scale pre-folded in Q): sacc[n][r] = S[q=fr][k=s0+n*16+kc*4+r]
        f32x4 sacc[2] = {};
        __builtin_amdgcn_s_setprio(1);
#pragma unroll
        for (int kq = 0; kq < 2; ++kq)
#pragma unroll
            for (int n = 0; n < 2; ++n) {
                int row = n * 16 + fr;
                bf16x8 bk = *(const bf16x8*)(lKb + row * 128 +
                                             ((kq * 64 + kc * 16) ^ ((row & 7) << 4)));
                sacc[n] = __builtin_amdgcn_mfma_f32_16x16x32_bf16(bk, aq[kq], sacc[n], 0, 0, 0);
            }
        __builtin_amdgcn_s_setprio(0);

        if (diag) {
#pragma unroll
            for (int n = 0; n < 2; ++n)
#pragma unroll
                for (int r = 0; r < 4; ++r)
                    if (s0 + n * 16 + kc * 4 + r > qrow) sacc[n][r] = -1e30f;
        }
        float rmax = -1e30f;
#pragma unroll
        for (int n = 0; n < 2; ++n)
#pragma unroll
            for (int r = 0; r < 4; ++r)
                rmax = fmaxf(rmax, sacc[n][r]);
        rmax = fmaxf(rmax, __shfl_xor(rmax, 16));
        rmax = fmaxf(rmax, __shfl_xor(rmax, 32));

        bool raise = rmax > mi_l + 8.0f;   // T13 defer-max (exp2 domain)
        float f = raise ? __builtin_exp2f(mi_l - rmax) : 1.0f;
        if (raise) mi_l = rmax;

        float rs = 0.f;
#pragma unroll
        for (int n = 0; n < 2; ++n)
#pragma unroll
            for (int r = 0; r < 4; ++r) {
                float p = __builtin_exp2f(sacc[n][r] - mi_l);
                sacc[n][r] = p;
                rs += p;
            }
        rs += __shfl_xor(rs, 16);
        rs += __shfl_xor(rs, 32);
        li_l = li_l * f + rs;

        if (__any(raise)) {
#pragma unroll
            for (int n8 = 0; n8 < 8; ++n8)
#pragma unroll
                for (int r = 0; r < 4; ++r) o[n8][r] *= f;
        }

        // pack P -> bf16 pairs: w32[n][w] = {P[k=n*16+kc*4+2w], [+1]}
        u32 w32[2][2];
#pragma unroll
        for (int n = 0; n < 2; ++n)
#pragma unroll
            for (int w = 0; w < 2; ++w) {
                u32 rpk;
                asm("v_cvt_pk_bf16_f32 %0, %1, %2"
                    : "=v"(rpk) : "v"(sacc[n][2 * w]), "v"(sacc[n][2 * w + 1]));
                w32[n][w] = rpk;
            }

        // redistribute: ap = P[k=kc*8+j][q=fr], j=0..7
        u32 a0 = (u32)__shfl((int)w32[0][0], srcA);
        u32 a1 = (u32)__shfl((int)w32[0][1], srcA);
        u32 a2 = (u32)__shfl((int)w32[0][0], srcB);
        u32 a3 = (u32)__shfl((int)w32[0][1], srcB);
        u32 b0 = (u32)__shfl((int)w32[1][0], srcA);
        u32 b1 = (u32)__shfl((int)w32[1][1], srcA);
        u32 b2 = (u32)__shfl((int)w32[1][0], srcB);
        u32 b3 = (u32)__shfl((int)w32[1][1], srcB);
        union { u32 u4[4]; bf16x8 v; } ap;
        ap.u4[0] = hi ? b0 : a0;
        ap.u4[1] = hi ? b1 : a1;
        ap.u4[2] = hi ? b2 : a2;
        ap.u4[3] = hi ? b3 : a3;

        // PV: O^T += V^T(d x 32k) x P  (8 mfma, full k=32 per call)
        __builtin_amdgcn_s_setprio(1);
#pragma unroll
        for (int n8 = 0; n8 < 8; ++n8) {
            int d = n8 * 16 + fr;
            int row = d >> 1;
            int colb = (d & 1) * 64 + kc * 16;
            bf16x8 bv = *(const bf16x8*)(lVb + row * 128 + (colb ^ ((row & 7) << 4)));
            o[n8] = __builtin_amdgcn_mfma_f32_16x16x32_bf16(bv, ap.v, o[n8], 0, 0, 0);
        }
        __builtin_amdgcn_s_setprio(0);
    };

    stage(0, tb);
    for (int t = tb; t < te; ++t) {
        int ib = (t - tb) & 1;
        if (t + 1 < te) {
            stage(ib ^ 1, t + 1);
            asm volatile("s_waitcnt vmcnt(3)" ::: "memory");
        } else {
            asm volatile("s_waitcnt vmcnt(0)" ::: "memory");
        }
        __builtin_amdgcn_sched_barrier(0);
        __builtin_amdgcn_s_barrier();
        __builtin_amdgcn_sched_barrier(0);
        compute((const char*)lK[ib], (const char*)lV[ib], t << 5, t >= ntot - 2);
        __builtin_amdgcn_s_barrier();
    }

    // epilogue: normalized O (fp16) + (m,l)
    const float inv_l = 1.0f / li_l;
    u16* Ob = Oc + ((size_t)(plane * 4 + chunk) * T_SEQ + qrow) * 128;
#pragma unroll
    for (int n8 = 0; n8 < 8; ++n8) {
        ushort4 w;
        w.x = f2h(o[n8][0] * inv_l);
        w.y = f2h(o[n8][1] * inv_l);
        w.z = f2h(o[n8][2] * inv_l);
        w.w = f2h(o[n8][3] * inv_l);
        *(ushort4*)(Ob + n8 * 16 + kc * 4) = w;
    }
    if (kc == 0)
        ml[(size_t)(plane * 4 + chunk) * T_SEQ + qrow] = make_float2(mi_l, li_l);
}

// ---------------- merge chunks + diff (y1 - lambda*y2) -> bf16 ----------------
__global__ __launch_bounds__(256) void merge_kernel(const u16* __restrict__ Oc,
                                                    const float2* __restrict__ ml,
                                                    const float* __restrict__ lamp,
                                                    u16* __restrict__ yc) {
    int uu = blockIdx.x * 256 + threadIdx.x;   // < 524288
    int t = uu >> 8, rem = uu & 255, h = rem >> 5, d4 = (rem & 31) * 4;
    int qt = t >> 6;                           // QBLK = 64
    int nc = (qt + 8) >> 3;                    // ceil((2qt+2)/16)
    float lamv = *lamp;
    float yv[2][4];
#pragma unroll
    for (int v = 0; v < 2; ++v) {
        int plane = v * 8 + h;
        float2 m_l[4];
        float M = -1e30f;
#pragma unroll
        for (int c = 0; c < 4; ++c)
            if (c < nc) {
                m_l[c] = ml[(size_t)(plane * 4 + c) * T_SEQ + t];
                M = fmaxf(M, m_l[c].x);
            }
        float den = 0.f, a0 = 0.f, a1 = 0.f, a2 = 0.f, a3 = 0.f;
#pragma unroll
        for (int c = 0; c < 4; ++c)
            if (c < nc) {
                float w = __builtin_exp2f(m_l[c].x - M) * m_l[c].y;
                den += w;
                ushort4 ov = *(const ushort4*)(Oc +
                    ((size_t)(plane * 4 + c) * T_SEQ + t) * 128 + d4);
                a0 += w * h2f(ov.x);
                a1 += w * h2f(ov.y);
                a2 += w * h2f(ov.z);
                a3 += w * h2f(ov.w);
            }
        float inv = 1.0f / den;
        yv[v][0] = a0 * inv; yv[v][1] = a1 * inv;
        yv[v][2] = a2 * inv; yv[v][3] = a3 * inv;
    }
    ushort4 o;
    o.x = f2bf(yv[0][0] - lamv * yv[1][0]);
    o.y = f2bf(yv[0][1] - lamv * yv[1][1]);
    o.z = f2bf(yv[0][2] - lamv * yv[1][2]);
    o.w = f2bf(yv[0][3] - lamv * yv[1][3]);
    *(ushort4*)(yc + (size_t)t * 1024 + h * 128 + d4) = o;
}

extern "C" void kernel_launch(void* const* d_in, const int* in_sizes, int n_in,
                              void* d_out, int out_size, void* d_ws, size_t ws_size,
                              hipStream_t stream) {
    const float* x   = (const float*)d_in[0];
    const float* Wq  = (const float*)d_in[1];
    const float* Wk  = (const float*)d_in[2];
    const float* Wv  = (const float*)d_in[3];
    const float* Wp  = (const float*)d_in[4];
    const float* lq1 = (const float*)d_in[5];
    const float* lk1 = (const float*)d_in[6];
    const float* lq2 = (const float*)d_in[7];
    const float* lk2 = (const float*)d_in[8];
    float* out = (float*)d_out;

    char* ws = (char*)d_ws;
    u16*    x_bf  = (u16*)(ws);                        //  4 MB
    u16*    wq_bf = (u16*)(ws + (4ull << 20));
    u16*    wk_bf = (u16*)(ws + (6ull << 20));
    u16*    wv_bf = (u16*)(ws + (8ull << 20));
    u16*    wp_bf = (u16*)(ws + (10ull << 20));
    u16*    vT_bf = (u16*)(ws + (12ull << 20));        //  4 MB
    u16*    q_bf  = (u16*)(ws + (16ull << 20));        //  4 MB
    u16*    k_bf  = (u16*)(ws + (20ull << 20));        //  4 MB
    u16*    Oc    = (u16*)(ws + (24ull << 20));        // 32 MB (fp16)
    float2* ml    = (float2*)(ws + (56ull << 20));     //  1 MB
    u16*    yc_bf = (u16*)(ws + (57ull << 20));        //  4 MB
    float*  cosT  = (float*)(ws + (61ull << 20));
    float*  sinT  = (float*)(ws + (61ull << 20) + (256ull << 10));
    float*  lam   = (float*)(ws + (61ull << 20) + (512ull << 10));

    prep<<<6401, 256, 0, stream>>>(x, Wq, Wk, Wv, Wp,
                                   x_bf, wq_bf, wk_bf, wv_bf, wp_bf,
                                   cosT, sinT, lq1, lk1, lq2, lk2, lam);

    gemm_qkv<<<dim3(24, 32), 256, 0, stream>>>(x_bf, wq_bf, wk_bf, wv_bf,
                                               cosT, sinT, q_bf, k_bf, vT_bf);

    attn_kernel<<<1280, 256, 0, stream>>>(q_bf, k_bf, vT_bf, Oc, ml);

    merge_kernel<<<2048, 256, 0, stream>>>(Oc, ml, lam, yc_bf);

    gemm_proj<<<dim3(8, 32), 256, 0, stream>>>(yc_bf, wp_bf, out);
}